// Round 7
// baseline (355.663 us; speedup 1.0000x reference)
//
#include <hip/hip_runtime.h>

typedef __attribute__((ext_vector_type(8))) short short8;
typedef __attribute__((ext_vector_type(4))) float floatx4;

#define FDIM 512
#define HDIM 256

__device__ __forceinline__ unsigned short f2bf(float f) {
  unsigned int u = __float_as_uint(f);
  u += 0x7fffu + ((u >> 16) & 1u);   // round-to-nearest-even
  return (unsigned short)(u >> 16);
}

__device__ __forceinline__ float bf2f(unsigned short u) {
  return __uint_as_float(((unsigned int)u) << 16);
}

__device__ __forceinline__ short8 pack2(float4 a, float4 b) {
  short8 r;
  r[0] = (short)f2bf(a.x); r[1] = (short)f2bf(a.y);
  r[2] = (short)f2bf(a.z); r[3] = (short)f2bf(a.w);
  r[4] = (short)f2bf(b.x); r[5] = (short)f2bf(b.y);
  r[6] = (short)f2bf(b.z); r[7] = (short)f2bf(b.w);
  return r;
}

__device__ __forceinline__ float fast_tanh(float x) {
  x = fminf(15.0f, fmaxf(-15.0f, x));
  float e = __expf(2.0f * x);
  return (e - 1.0f) / (e + 1.0f);
}

// K0: pack W1 [512][256] fp32 -> W1B bf16 fragment-major:
// element index = s*8192 + oct*2048 + col*8 + e   (k = s*32 + oct*8 + e)
// Blocks < 128 also zero out (re-poison safety; out accumulated by atomics).
__global__ void __launch_bounds__(256)
k0_pack_w1(const float* __restrict__ W1, unsigned short* __restrict__ W1B,
           float* __restrict__ out) {
  int tid = threadIdx.x;
  int idx = blockIdx.x * 256 + tid;           // 0..131071
  if (blockIdx.x < 128) out[blockIdx.x * 256 + tid] = 0.0f;   // 32768 floats
  int k = idx >> 8;                           // 0..511
  int n = idx & 255;
  int s = k >> 5, r = k & 31, oct = r >> 3, e = r & 7;
  W1B[s * 8192 + oct * 2048 + n * 8 + e] = f2bf(W1[idx]);
}

// K1 mono: BARRIER-FREE fused scores + exp + unnormalized bag-sum.
// One wave owns 16 rows x ALL 256 cols. No LDS, no __syncthreads, no asm.
//  - A: lane (l4,l15) reads X[row0+l15][t*32+l4*8 .. +8] straight from global
//    (32 B fp32), packs to bf16, and RETAINS af[16] in registers (64 VGPR)
//    for phase 2 -> X is streamed exactly once, no second pass anywhere.
//  - B: 16 fragments/step per-lane from fragment-major W1B; every wave on a
//    CU walks the same 16 KB step-tile -> L1/L2-hot.
//  - acc[16] (64 VGPR): C[c = n*16+l15][r = l4*4+j]  (same MFMA mapping as
//    the verified R0-R5 kernels; m-tiles 4->1, n-tiles 4->16).
//  - epilogue: per-lane tanh/W2 partial, l15-butterfly -> all lanes hold the
//    scores of their l4-group's 4 rows; es via 4 shuffles; Z -> partials[wg].
//  - phase 2 from retained af: per step, weighted l15-butterfly reduce of
//    es_row * x_row[k], atomics from l15==0 lanes. Ragged bags handled by a
//    uniform segment loop (weights masked per segment).
// Spill safety (R4 lesson): no min-waves bound; compiler-scheduled loads
// (no manual vmcnt ledger), so even a spill is merely slow, never wrong.
__global__ void __launch_bounds__(256)
k1_mono(const float* __restrict__ X,
        const unsigned short* __restrict__ W1B,
        const float* __restrict__ b1,
        const float* __restrict__ W2,
        const int* __restrict__ bag_sizes,
        int nbags,
        float* __restrict__ out,
        float* __restrict__ partials) {
  const int tid  = threadIdx.x;
  const int wid  = tid >> 6;
  const int lane = tid & 63;
  const int l15  = lane & 15;
  const int l4   = lane >> 4;
  const int wg   = blockIdx.x * 4 + wid;       // global wave id 0..8191
  const long row0 = (long)wg * 16;

  floatx4 acc[16];
  #pragma unroll
  for (int n = 0; n < 16; ++n) acc[n] = (floatx4){0.f, 0.f, 0.f, 0.f};

  short8 af[16];                               // retained bf16 X fragments

  const float* xsrc = X + (row0 + l15) * FDIM + l4 * 8;
  const unsigned short* bb0 = W1B + l4 * 2048 + l15 * 8;

  #pragma unroll
  for (int t = 0; t < 16; ++t) {
    float4 a0 = *(const float4*)(xsrc + t * 32);
    float4 a1 = *(const float4*)(xsrc + t * 32 + 4);
    af[t] = pack2(a0, a1);
    const unsigned short* bb = bb0 + t * 8192;
    #pragma unroll
    for (int n = 0; n < 16; ++n) {
      short8 bfr = *(const short8*)(bb + n * 128);
      acc[n] = __builtin_amdgcn_mfma_f32_16x16x32_bf16(af[t], bfr, acc[n], 0, 0, 0);
    }
  }

  // ---- scores: H[c = n*16+l15][r = l4*4+j] in acc[n][j] ----
  float rowacc[4] = {0.f, 0.f, 0.f, 0.f};
  #pragma unroll
  for (int n = 0; n < 16; ++n) {
    int c = n * 16 + l15;
    float b1c = b1[c];
    float w2c = W2[c];
    #pragma unroll
    for (int j = 0; j < 4; ++j)
      rowacc[j] = fmaf(fast_tanh(acc[n][j] + b1c), w2c, rowacc[j]);
  }
  #pragma unroll
  for (int j = 0; j < 4; ++j) {
    float v = rowacc[j];
    v += __shfl_xor(v, 1, 64);
    v += __shfl_xor(v, 2, 64);
    v += __shfl_xor(v, 4, 64);
    v += __shfl_xor(v, 8, 64);
    rowacc[j] = v;          // full score of row l4*4+j (uniform in l15-group)
  }
  float esj[4];
  #pragma unroll
  for (int j = 0; j < 4; ++j) esj[j] = __expf(rowacc[j]);

  // wave partial Z
  float s4 = esj[0] + esj[1] + esj[2] + esj[3];
  s4 += __shfl_xor(s4, 16, 64);
  s4 += __shfl_xor(s4, 32, 64);
  if (lane == 0) partials[wg] = s4;

  // es of row l15 (for weighting this lane's retained fragments)
  int srcl = (l15 >> 2) << 4;                  // a lane of group l4 = l15>>2
  float e0 = __shfl(esj[0], srcl, 64);
  float e1 = __shfl(esj[1], srcl, 64);
  float e2 = __shfl(esj[2], srcl, 64);
  float e3 = __shfl(esj[3], srcl, 64);
  float eA = (l15 & 1) ? e1 : e0;
  float eB = (l15 & 1) ? e3 : e2;
  float es_my = (l15 & 2) ? eB : eA;

  // ---- phase 2: out[bag] += sum_r es_r * x_r  (unnormalized, bf16 x) ----
  int bag = 0; long cum = 0;
  while (bag + 1 < nbags && cum + (long)bag_sizes[bag] <= row0) {
    cum += bag_sizes[bag]; ++bag;
  }
  long bagEnd = cum + (long)bag_sizes[bag];

  int rs = 0;
  while (rs < 16) {                            // uniform across the wave
    int se = (int)(bagEnd - row0 < 16 ? bagEnd - row0 : 16);
    if (se < rs) se = rs;
    float wme = (l15 >= rs && l15 < se) ? es_my : 0.f;
    float* obase = out + (long)bag * FDIM;
    bool doatom = (l15 == 0) && (se > rs);
    #pragma unroll
    for (int t = 0; t < 16; ++t) {
      float p[8];
      #pragma unroll
      for (int e = 0; e < 8; ++e)
        p[e] = bf2f((unsigned short)af[t][e]) * wme;
      #pragma unroll
      for (int e = 0; e < 8; ++e) {
        p[e] += __shfl_xor(p[e], 1, 64);
        p[e] += __shfl_xor(p[e], 2, 64);
        p[e] += __shfl_xor(p[e], 4, 64);
        p[e] += __shfl_xor(p[e], 8, 64);
      }
      if (doatom) {
        float* op = obase + t * 32 + l4 * 8;
        #pragma unroll
        for (int e = 0; e < 8; ++e) atomicAdd(op + e, p[e]);
      }
    }
    rs = se;
    if (rs < 16) {
      ++bag;
      if (bag >= nbags) { bagEnd = row0 + 16; bag = nbags - 1; }
      else bagEnd += (long)bag_sizes[bag];
    }
  }
}

// K2: Z = sum(partials) (redundant per block); out *= 1/Z
__global__ void __launch_bounds__(256)
k2_scale(const float* __restrict__ partials, int nparts, float* __restrict__ out) {
  __shared__ float wred[4];
  int tid = threadIdx.x;
  float sL = 0.f;
  for (int j = tid; j < nparts; j += 256) sL += partials[j];
  #pragma unroll
  for (int m = 1; m < 64; m <<= 1) sL += __shfl_xor(sL, m, 64);
  if ((tid & 63) == 0) wred[tid >> 6] = sL;
  __syncthreads();
  float invZ = 1.0f / (wred[0] + wred[1] + wred[2] + wred[3]);
  int i = blockIdx.x * 256 + tid;
  out[i] = out[i] * invZ;
}

extern "C" void kernel_launch(void* const* d_in, const int* in_sizes, int n_in,
                              void* d_out, int out_size, void* d_ws, size_t ws_size,
                              hipStream_t stream) {
  const float* X         = (const float*)d_in[0];
  const int*   bag_sizes = (const int*)d_in[1];
  const float* W1        = (const float*)d_in[2];
  const float* b1        = (const float*)d_in[3];
  const float* W2        = (const float*)d_in[4];
  // b2 (d_in[5]) cancels in the global softmax — unused.
  float* out = (float*)d_out;

  const int T     = in_sizes[0] / FDIM;   // 131072
  const int nbags = in_sizes[1];          // 64
  const int nblk  = T / 64;               // 2048 blocks x 4 waves x 16 rows
  const int nwave = T / 16;               // 8192

  char* ws = (char*)d_ws;
  unsigned short* W1B = (unsigned short*)ws;                     // 262144 B
  float* partials = (float*)(ws + 262144);                       // 32768 B

  hipLaunchKernelGGL(k0_pack_w1, dim3(512), dim3(256), 0, stream, W1, W1B, out);
  hipLaunchKernelGGL(k1_mono, dim3(nblk), dim3(256), 0, stream,
                     X, W1B, b1, W2, bag_sizes, nbags, out, partials);
  hipLaunchKernelGGL(k2_scale, dim3((nbags * FDIM) / 256), dim3(256), 0, stream,
                     partials, nwave, out);
}

// Round 8
// 147.773 us; speedup vs baseline: 2.4068x; 2.4068x over previous
//
#include <hip/hip_runtime.h>

typedef __attribute__((ext_vector_type(8))) short short8;
typedef __attribute__((ext_vector_type(4))) float floatx4;

#define FDIM 512
#define HDIM 256

__device__ __forceinline__ unsigned short f2bf(float f) {
  unsigned int u = __float_as_uint(f);
  u += 0x7fffu + ((u >> 16) & 1u);   // round-to-nearest-even
  return (unsigned short)(u >> 16);
}

__device__ __forceinline__ float bf2f(unsigned short u) {
  return __uint_as_float(((unsigned int)u) << 16);
}

__device__ __forceinline__ short8 pack2(floatx4 a, floatx4 b) {
  short8 r;
  r[0] = (short)f2bf(a[0]); r[1] = (short)f2bf(a[1]);
  r[2] = (short)f2bf(a[2]); r[3] = (short)f2bf(a[3]);
  r[4] = (short)f2bf(b[0]); r[5] = (short)f2bf(b[1]);
  r[6] = (short)f2bf(b[2]); r[7] = (short)f2bf(b[3]);
  return r;
}

__device__ __forceinline__ float fast_tanh(float x) {
  x = fminf(15.0f, fmaxf(-15.0f, x));
  float e = __expf(2.0f * x);
  return (e - 1.0f) / (e + 1.0f);
}

#define VM(n) asm volatile("s_waitcnt vmcnt(" #n ")" ::: "memory")

// A: 2 x global_load_dwordx4 (8 floats), counted in the manual vmcnt ledger.
#define GLOAD_A(r0, r1, p)                                                     \
  do {                                                                         \
    asm volatile("global_load_dwordx4 %0, %1, off"                             \
                 : "=v"(r0) : "v"(p) : "memory");                              \
    asm volatile("global_load_dwordx4 %0, %1, off offset:16"                   \
                 : "=v"(r1) : "v"(p) : "memory");                              \
  } while (0)

// B: 4 x global_load_dwordx4 (4 short8 fragments, 16-col stride = 256 B).
#define GLOAD_B(r, p)                                                          \
  do {                                                                         \
    asm volatile("global_load_dwordx4 %0, %1, off"                             \
                 : "=v"(r[0]) : "v"(p) : "memory");                            \
    asm volatile("global_load_dwordx4 %0, %1, off offset:256"                  \
                 : "=v"(r[1]) : "v"(p) : "memory");                            \
    asm volatile("global_load_dwordx4 %0, %1, off offset:512"                  \
                 : "=v"(r[2]) : "v"(p) : "memory");                            \
    asm volatile("global_load_dwordx4 %0, %1, off offset:768"                  \
                 : "=v"(r[3]) : "v"(p) : "memory");                            \
  } while (0)

// K0: pack W1 [512][256] fp32 -> W1B bf16 fragment-major:
// element index = s*8192 + oct*2048 + n*8 + e   (k = s*32 + oct*8 + e)
// Blocks < 128 also zero out (re-poison safety; out accumulated by atomics).
__global__ void __launch_bounds__(256)
k0_pack_w1(const float* __restrict__ W1, unsigned short* __restrict__ W1B,
           float* __restrict__ out) {
  int tid = threadIdx.x;
  int idx = blockIdx.x * 256 + tid;           // 0..131071
  if (blockIdx.x < 128) out[blockIdx.x * 256 + tid] = 0.0f;   // 32768 floats
  int k = idx >> 8;                           // 0..511
  int n = idx & 255;
  int s = k >> 5, r = k & 31, oct = r >> 3, e = r & 7;
  W1B[s * 8192 + oct * 2048 + n * 8 + e] = f2bf(W1[idx]);
}

// K1: es = exp(score) per row + per-block partial Z; optionally (WX) also
// persists the bf16-packed X rows to Xb (row-major [T][512] bf16) so the
// bag-sum pass streams HALF the bytes (and mostly L3-hot).
// Structure = R5-proven: 64 rows/block, 4 waves, BK=32, 16 steps, LDS ~9 KB,
// B in registers, counted-vmcnt pipeline, no min-waves cap (R4 spill lesson).
//
// vmcnt ledger WITH store (A=2 ops, B=4 ops, S=1 store; in-order retire):
//   prologue: A0(2) B0(4) A1(2) = 8 outstanding
//   step t: W1-wait retires A(t); then pack -> ds_write -> STORE S(t);
//           barrier; issue B(t+1)(4), A(t+2)(2); W2-wait retires B(t).
//   t=0:  W1 VM(6)  [A0,B0,A1]=8        W2 VM(9)  [B0 + A1,S0,B1,A2=9]
//   t=1..13: W1 VM(7) [A(t)2,S(t-1),B(t)4,A(t+1)2=9 -> keep 7]
//            W2 VM(9) [retires S(t-1)+B(t) of 14]
//   t=14: W1 VM(7); no A16 issue; W2 VM(7)  [A15,S14,B15 newer]
//   t=15: W1 VM(5); no issues;    W2 VM(1)  [S15 newer]
//   post-loop VM(0) drains S15 (store-data regs freed only then).
// Store-data regs: two named alternating short8 (a0s/a1s) + keep-alive asm
// after each W2 — S(t) retires at W2(t+1), before a repack at t+2, and the
// keep-alives stop the allocator reusing an in-flight store's registers.
// Without WX the ledger collapses to R5's proven constants (6/4, 8/6/0).
template <bool WX>
__global__ void __launch_bounds__(256, 2)
k1_scores(const float* __restrict__ X,
          const unsigned short* __restrict__ W1B,
          const float* __restrict__ b1,
          const float* __restrict__ W2,
          unsigned short* __restrict__ Xb,
          float* __restrict__ es,
          float* __restrict__ partials) {
  __shared__ __align__(16) unsigned short As[2][2048];  // [buf][row64*32k] = 8 KB
  __shared__ float scpart[256];                         // [wn][row64]

  const int tid  = threadIdx.x;
  const int wn   = tid >> 6;          // 0..3 col-group
  const int lane = tid & 63;
  const int l15  = lane & 15;
  const int l4   = lane >> 4;
  const long row0 = (long)blockIdx.x * 64;

  floatx4 acc[4][4];
  #pragma unroll
  for (int m = 0; m < 4; m++)
    #pragma unroll
    for (int n = 0; n < 4; n++)
      acc[m][n] = (floatx4){0.f, 0.f, 0.f, 0.f};

  // A staging map: thread -> (row = tid>>2, octet = tid&3 -> 8 consecutive k)
  const int arow = tid >> 2;                    // 0..63
  const int aoct = tid & 3;                     // octet within 32-k step
  const float* xsrc = X + (row0 + arow) * FDIM + aoct * 8;
  unsigned short* xbdst = Xb + (row0 + arow) * FDIM + aoct * 8;
  // B fragment base for this lane: oct = l4, col = wn*64 + l15
  const unsigned short* bsrc = W1B + l4 * 2048 + (wn * 64 + l15) * 8;

  floatx4 va0, va1, vb0, vb1;            // 2 rotating A sets (depth-2)
  short8 br0[4], br1[4];                 // 2 rotating B sets (depth-1)
  short8 a0s = {0,0,0,0,0,0,0,0}, a1s = {0,0,0,0,0,0,0,0};  // store alternates

  // Prologue issue order: A(0), B(0)->set0, A(1)  => 8 outstanding
  GLOAD_A(va0, va1, xsrc);
  GLOAD_B(br0, bsrc);
  GLOAD_A(vb0, vb1, xsrc + 32);

  #pragma unroll
  for (int t = 0; t < 16; ++t) {
    // ---- W1: retire A(t) regs ----
    if constexpr (WX) {
      if (t == 0)      VM(6);
      else if (t < 15) VM(7);
      else             VM(5);
    } else {
      if (t < 15) VM(6);
      else        VM(4);
    }
    __builtin_amdgcn_sched_barrier(0);
    {
      if ((t & 1) == 0) {
        a0s = pack2(va0, va1);
        *(short8*)(&As[0][arow * 32 + aoct * 8]) = a0s;
        if constexpr (WX)
          asm volatile("global_store_dwordx4 %0, %1, off"
                       :: "v"(xbdst + t * 32), "v"(a0s) : "memory");
      } else {
        a1s = pack2(vb0, vb1);
        *(short8*)(&As[1][arow * 32 + aoct * 8]) = a1s;
        if constexpr (WX)
          asm volatile("global_store_dwordx4 %0, %1, off"
                       :: "v"(xbdst + t * 32), "v"(a1s) : "memory");
      }
    }
    asm volatile("s_waitcnt lgkmcnt(0)" ::: "memory");
    __builtin_amdgcn_sched_barrier(0);
    __builtin_amdgcn_s_barrier();
    // ---- issue next loads (stay in flight across barriers) ----
    if (t < 15) {                       // B(t+1) -> other set
      const unsigned short* bp = bsrc + (t + 1) * 8192;
      if (((t + 1) & 1) == 0) GLOAD_B(br0, bp);
      else                    GLOAD_B(br1, bp);
    }
    if (t < 14) {                       // A(t+2) -> just-consumed set
      const float* pp = xsrc + (t + 2) * 32;
      if ((t & 1) == 0) GLOAD_A(va0, va1, pp);
      else              GLOAD_A(vb0, vb1, pp);
    }
    // ---- W2: retire B(t) regs (and, WX, S(t-1)) ----
    if constexpr (WX) {
      if (t < 14)       VM(9);
      else if (t == 14) VM(7);
      else              VM(1);
    } else {
      if (t < 14)       VM(8);
      else if (t == 14) VM(6);
      else              VM(0);
    }
    __builtin_amdgcn_sched_barrier(0);
    if constexpr (WX) asm volatile("" :: "v"(a0s), "v"(a1s));  // keep-alive
    // ---- compute(t): 4 A-frags x 4 B-frags, 16 MFMA per wave ----
    short8 af[4];
    #pragma unroll
    for (int m = 0; m < 4; ++m)
      af[m] = *(const short8*)(&As[t & 1][(m * 16 + l15) * 32 + l4 * 8]);
    const short8* bcur = ((t & 1) == 0) ? br0 : br1;
    #pragma unroll
    for (int n = 0; n < 4; ++n)
      #pragma unroll
      for (int m = 0; m < 4; ++m)
        acc[m][n] = __builtin_amdgcn_mfma_f32_16x16x32_bf16(af[m], bcur[n], acc[m][n], 0, 0, 0);
  }
  if constexpr (WX) {
    asm volatile("" :: "v"(a0s), "v"(a1s));   // keep-alive until drain
    VM(0);                                    // drain S15 (frees store regs)
  }

  // epilogue: score = sum_c tanh(H + b1[c]) * W2[c]  over this wave's 64 cols
  float rowacc[16];
  #pragma unroll
  for (int i = 0; i < 16; i++) rowacc[i] = 0.f;
  #pragma unroll
  for (int n = 0; n < 4; n++) {
    int c = wn * 64 + n * 16 + l15;
    float b1c = b1[c];
    float w2c = W2[c];
    #pragma unroll
    for (int m = 0; m < 4; m++)
      #pragma unroll
      for (int j = 0; j < 4; j++) {
        float h = fast_tanh(acc[m][n][j] + b1c);
        rowacc[m * 4 + j] = fmaf(h, w2c, rowacc[m * 4 + j]);
      }
  }
  #pragma unroll
  for (int i = 0; i < 16; i++) {
    float v = rowacc[i];
    v += __shfl_xor(v, 1, 64);
    v += __shfl_xor(v, 2, 64);
    v += __shfl_xor(v, 4, 64);
    v += __shfl_xor(v, 8, 64);
    rowacc[i] = v;
  }
  if (l15 == 0) {
    #pragma unroll
    for (int m = 0; m < 4; m++)
      #pragma unroll
      for (int j = 0; j < 4; j++)
        scpart[wn * 64 + m * 16 + l4 * 4 + j] = rowacc[m * 4 + j];
  }
  __syncthreads();

  // es (global) + block partial Z  (first wave only)
  if (tid < 64) {
    float sv = scpart[0 * 64 + tid] + scpart[1 * 64 + tid] +
               scpart[2 * 64 + tid] + scpart[3 * 64 + tid];
    float ev = __expf(sv);
    es[row0 + tid] = ev;
    float v = ev;
    v += __shfl_xor(v, 1, 64);
    v += __shfl_xor(v, 2, 64);
    v += __shfl_xor(v, 4, 64);
    v += __shfl_xor(v, 8, 64);
    v += __shfl_xor(v, 16, 64);
    v += __shfl_xor(v, 32, 64);
    if (tid == 0) partials[blockIdx.x] = v;
  }
}

// K3-bf16: out[bag] += invZ * sum es[i] * Xb[i]  (bf16 X copy, L3-hot).
// 16 chunks/bag; 256 threads = 64 feature-cols (8 feats, 16 B) x 4 parities.
// Wave 3 computes invZ from partials concurrently with streaming (k2b folded).
__global__ void __launch_bounds__(256)
k3_bagsum_bf16(const unsigned short* __restrict__ Xb,
               const int* __restrict__ bag_sizes,
               const float* __restrict__ es,
               const float* __restrict__ partials, int nparts,
               float* __restrict__ out, int nbags) {
  __shared__ float pacc[3][512];
  __shared__ float invZ_s;
  const int tid = threadIdx.x;
  const int fc  = tid & 63;            // feature col: feats fc*8..fc*8+7
  const int par = tid >> 6;            // wave index = row parity

  if (par == 3) {                      // invZ (partials small + L2-hot)
    float s = 0.f;
    for (int j = fc; j < nparts; j += 64) s += partials[j];
    #pragma unroll
    for (int m = 1; m < 64; m <<= 1) s += __shfl_xor(s, m, 64);
    if (fc == 0) invZ_s = 1.0f / s;
  }

  const int bag = blockIdx.x >> 4;
  const int ic  = blockIdx.x & 15;
  int start = 0;
  for (int b = 0; b < bag; ++b) start += bag_sizes[b];
  const int size = bag_sizes[bag];
  const int end = start + size;
  const int chunk = (size + 15) >> 4;
  int i0 = start + ic * chunk;
  int i1 = min(i0 + chunk, end);

  float a[8];
  #pragma unroll
  for (int e = 0; e < 8; ++e) a[e] = 0.f;
  for (int i = i0 + par; i < i1; i += 4) {
    float w = es[i];
    short8 xv = *(const short8*)(Xb + (size_t)i * FDIM + fc * 8);
    #pragma unroll
    for (int e = 0; e < 8; ++e)
      a[e] = fmaf(bf2f((unsigned short)xv[e]), w, a[e]);
  }
  if (par != 0) {
    #pragma unroll
    for (int e = 0; e < 8; ++e) pacc[par - 1][fc * 8 + e] = a[e];
  }
  __syncthreads();
  if (par == 0) {
    float invZ = invZ_s;
    float* op = out + (size_t)bag * FDIM + fc * 8;
    #pragma unroll
    for (int e = 0; e < 8; ++e) {
      float tot = a[e] + pacc[0][fc * 8 + e] + pacc[1][fc * 8 + e] +
                  pacc[2][fc * 8 + e];
      atomicAdd(op + e, tot * invZ);
    }
  }
}

// ---- fallback path (ws too small for Xb): R5-proven k2b + fp32 k3 ----
__global__ void __launch_bounds__(256)
k2b_finish(const float* __restrict__ partials, int nparts, float* __restrict__ invZ) {
  int tid = threadIdx.x;
  float s = 0.f;
  for (int j = tid; j < nparts; j += 256) s += partials[j];
  #pragma unroll
  for (int m = 1; m < 64; m <<= 1) s += __shfl_xor(s, m, 64);
  __shared__ float wred[4];
  if ((tid & 63) == 0) wred[tid >> 6] = s;
  __syncthreads();
  if (tid == 0) invZ[0] = 1.0f / (wred[0] + wred[1] + wred[2] + wred[3]);
}

__global__ void __launch_bounds__(256)
k3_bagsum(const float* __restrict__ X, const int* __restrict__ bag_sizes,
          const float* __restrict__ es, const float* __restrict__ invZp,
          float* __restrict__ out, int nbags) {
  const int tid = threadIdx.x;
  const int f   = (tid & 127) * 4;
  const int r   = tid >> 7;
  const int bag = blockIdx.x >> 4;
  const int ic  = blockIdx.x & 15;
  int start = 0;
  for (int b = 0; b < bag; ++b) start += bag_sizes[b];
  const int size = bag_sizes[bag];
  const int end = start + size;
  const int chunk = (size + 15) >> 4;
  int i0 = start + ic * chunk;
  int i1 = min(i0 + chunk, end);
  float ax = 0.f, ay = 0.f, az = 0.f, aw = 0.f;
  for (int i = i0 + r; i < i1; i += 2) {
    float w = es[i];
    float4 x = *(const float4*)(X + (size_t)i * FDIM + f);
    ax = fmaf(x.x, w, ax); ay = fmaf(x.y, w, ay);
    az = fmaf(x.z, w, az); aw = fmaf(x.w, w, aw);
  }
  __shared__ float4 red[128];
  if (r == 1) red[tid & 127] = (float4){ax, ay, az, aw};
  __syncthreads();
  if (r == 0) {
    float4 o = red[tid];
    float invZ = invZp[0];
    ax = (ax + o.x) * invZ; ay = (ay + o.y) * invZ;
    az = (az + o.z) * invZ; aw = (aw + o.w) * invZ;
    float* op = out + (size_t)bag * FDIM + f;
    atomicAdd(op + 0, ax); atomicAdd(op + 1, ay);
    atomicAdd(op + 2, az); atomicAdd(op + 3, aw);
  }
}

extern "C" void kernel_launch(void* const* d_in, const int* in_sizes, int n_in,
                              void* d_out, int out_size, void* d_ws, size_t ws_size,
                              hipStream_t stream) {
  const float* X         = (const float*)d_in[0];
  const int*   bag_sizes = (const int*)d_in[1];
  const float* W1        = (const float*)d_in[2];
  const float* b1        = (const float*)d_in[3];
  const float* W2        = (const float*)d_in[4];
  // b2 (d_in[5]) cancels in the global softmax — unused.
  float* out = (float*)d_out;

  const int T     = in_sizes[0] / FDIM;   // 131072
  const int nbags = in_sizes[1];          // 64
  const int nblk  = T / 64;               // 2048

  char* ws = (char*)d_ws;
  unsigned short* W1B = (unsigned short*)ws;                     // 262144 B
  float* es       = (float*)(ws + 262144);                       // 524288 B
  float* partials = (float*)(ws + 262144 + 524288);              // 8192 B
  float* invZ     = (float*)(ws + 262144 + 524288 + 8192);       // 4 B
  unsigned short* Xb = (unsigned short*)(ws + 1048576);          // 134217728 B
  const size_t NEED = 1048576 + (size_t)T * FDIM * 2;

  hipLaunchKernelGGL(k0_pack_w1, dim3(512), dim3(256), 0, stream, W1, W1B, out);
  if (ws_size >= NEED) {
    hipLaunchKernelGGL(k1_scores<true>, dim3(nblk), dim3(256), 0, stream,
                       X, W1B, b1, W2, Xb, es, partials);
    hipLaunchKernelGGL(k3_bagsum_bf16, dim3(nbags * 16), dim3(256), 0, stream,
                       Xb, bag_sizes, es, partials, nblk, out, nbags);
  } else {
    hipLaunchKernelGGL(k1_scores<false>, dim3(nblk), dim3(256), 0, stream,
                       X, W1B, b1, W2, Xb, es, partials);
    hipLaunchKernelGGL(k2b_finish, dim3(1), dim3(256), 0, stream, partials, nblk, invZ);
    hipLaunchKernelGGL(k3_bagsum, dim3(nbags * 16), dim3(256), 0, stream,
                       X, bag_sizes, es, invZ, out, nbags);
  }
}

// Round 9
// 135.556 us; speedup vs baseline: 2.6237x; 1.0901x over previous
//
#include <hip/hip_runtime.h>

typedef __attribute__((ext_vector_type(8))) short short8;
typedef __attribute__((ext_vector_type(4))) float floatx4;

#define FDIM 512
#define HDIM 256

__device__ __forceinline__ unsigned short f2bf(float f) {
  unsigned int u = __float_as_uint(f);
  u += 0x7fffu + ((u >> 16) & 1u);   // round-to-nearest-even
  return (unsigned short)(u >> 16);
}

__device__ __forceinline__ short8 pack2(floatx4 a, floatx4 b) {
  short8 r;
  r[0] = (short)f2bf(a[0]); r[1] = (short)f2bf(a[1]);
  r[2] = (short)f2bf(a[2]); r[3] = (short)f2bf(a[3]);
  r[4] = (short)f2bf(b[0]); r[5] = (short)f2bf(b[1]);
  r[6] = (short)f2bf(b[2]); r[7] = (short)f2bf(b[3]);
  return r;
}

__device__ __forceinline__ float fast_tanh(float x) {
  x = fminf(15.0f, fmaxf(-15.0f, x));
  float e = __expf(2.0f * x);
  return (e - 1.0f) / (e + 1.0f);
}

// A: 2 x global_load_dwordx4 (8 floats), counted in the manual vmcnt ledger.
#define GLOAD_A(r0, r1, p)                                                     \
  do {                                                                         \
    asm volatile("global_load_dwordx4 %0, %1, off"                             \
                 : "=v"(r0) : "v"(p) : "memory");                              \
    asm volatile("global_load_dwordx4 %0, %1, off offset:16"                   \
                 : "=v"(r1) : "v"(p) : "memory");                              \
  } while (0)

// B: 4 x global_load_dwordx4 (4 short8 fragments, 16-col stride = 256 B).
#define GLOAD_B(r, p)                                                          \
  do {                                                                         \
    asm volatile("global_load_dwordx4 %0, %1, off"                             \
                 : "=v"(r[0]) : "v"(p) : "memory");                            \
    asm volatile("global_load_dwordx4 %0, %1, off offset:256"                  \
                 : "=v"(r[1]) : "v"(p) : "memory");                            \
    asm volatile("global_load_dwordx4 %0, %1, off offset:512"                  \
                 : "=v"(r[2]) : "v"(p) : "memory");                            \
    asm volatile("global_load_dwordx4 %0, %1, off offset:768"                  \
                 : "=v"(r[3]) : "v"(p) : "memory");                            \
  } while (0)

// K0: pack W1 fp32 -> W1B bf16 fragment-major; zero `out` (fallback path's
// atomics) and, when given, outAcc (rare-segment atomic spillover).
__global__ void __launch_bounds__(256)
k0_pack_w1(const float* __restrict__ W1, unsigned short* __restrict__ W1B,
           float* __restrict__ out, float* __restrict__ outAcc) {
  int tid = threadIdx.x;
  int idx = blockIdx.x * 256 + tid;           // 0..131071
  if (blockIdx.x < 128) {
    out[blockIdx.x * 256 + tid] = 0.0f;       // 32768 floats
    if (outAcc) outAcc[blockIdx.x * 256 + tid] = 0.0f;
  }
  int k = idx >> 8;                           // 0..511
  int n = idx & 255;
  int s = k >> 5, r = k & 31, oct = r >> 3, e = r & 7;
  W1B[s * 8192 + oct * 2048 + n * 8 + e] = f2bf(W1[idx]);
}

// K1: scores + es + (FUSE) per-bag PRIVATE partial sums from retained regs.
// Phase 1 = R5-proven: 64 rows/block, 4 waves, BK=32, 16 steps, B in regs,
// counted-vmcnt ledger (UNCHANGED: no vmem ops added inside counted region):
//   prologue A0(2) B0(4) A1(2)=8; head VM(6) retires A(t) (t=15: VM(4));
//   post-barrier issue B(t+1), A(t+2); compute-wait VM(8)/VM(6)/VM(0).
// FUSE additions (all AFTER the counted region):
//   xa[16] retains this thread's own staged fragments
//   X[row0+arow][t*32+aoct*8+e]  (+64 VGPR; peak ~210 < 256 cap -> no spill,
//   R4 lesson: spills inside the counted region corrupt the ledger).
//   Phase 2 per segment: p[8] = es[arow]*xa[t]; shfl_xor 4,8 folds 4 rows;
//   16 lanes/wave write pacc[16][512] (aliases dead As+scpart); final sum of
//   16 groups -> NON-ATOMIC partial_out[block][slot][512] + bagid.
//   (R7 lesson: global atomics into 64x512 addrs serialize; private commits
//   + tiny k2 reduce avoid all contention.) >2 segments/block (tiny bags):
//   atomicAdd spillover into outAcc (zeroed by k0).
template <bool FUSE>
__global__ void __launch_bounds__(256, 2)
k1_scores(const float* __restrict__ X,
          const unsigned short* __restrict__ W1B,
          const float* __restrict__ b1,
          const float* __restrict__ W2,
          float* __restrict__ es,
          float* __restrict__ partials,
          float* __restrict__ partial_out,
          int* __restrict__ bagid,
          float* __restrict__ outAcc,
          const int* __restrict__ bag_sizes,
          int nbags) {
  // LDS: As [2][2048]us @0 (8 KB) | scpart 256f @8192 | (FUSE) pacc[16][512]f
  // @0 ALIASES As+scpart (both dead before phase 2) | es_s 64f at tail.
  __shared__ __align__(16) unsigned char smem[FUSE ? 33024 : 9472];
  unsigned short (*As)[2048] = (unsigned short(*)[2048])smem;
  float* scpart = (float*)(smem + 8192);
  float* es_s   = (float*)(smem + (FUSE ? 32768 : 9216));

  const int tid  = threadIdx.x;
  const int wn   = tid >> 6;          // 0..3 col-group
  const int lane = tid & 63;
  const int l15  = lane & 15;
  const int l4   = lane >> 4;
  const long row0 = (long)blockIdx.x * 64;

  floatx4 acc[4][4];
  #pragma unroll
  for (int m = 0; m < 4; m++)
    #pragma unroll
    for (int n = 0; n < 4; n++)
      acc[m][n] = (floatx4){0.f, 0.f, 0.f, 0.f};

  // A staging map: thread -> (row = tid>>2, octet = tid&3 -> 8 consecutive k)
  const int arow = tid >> 2;                    // 0..63
  const int aoct = tid & 3;                     // octet within 32-k step
  const float* xsrc = X + (row0 + arow) * FDIM + aoct * 8;
  // B fragment base for this lane: oct = l4, col = wn*64 + l15
  const unsigned short* bsrc = W1B + l4 * 2048 + (wn * 64 + l15) * 8;

  floatx4 va0, va1, vb0, vb1;            // 2 rotating A sets (depth-2)
  short8 br0[4], br1[4];                 // 2 rotating B sets (depth-1)
  short8 xa[16];                         // FUSE: retained own fragments

  // Prologue issue order: A(0), B(0)->set0, A(1)  => 8 outstanding
  GLOAD_A(va0, va1, xsrc);
  GLOAD_B(br0, bsrc);
  GLOAD_A(vb0, vb1, xsrc + 32);

  #pragma unroll
  for (int t = 0; t < 16; ++t) {
    // ---- retire A(t) regs ----
    if (t < 15) asm volatile("s_waitcnt vmcnt(6)" ::: "memory");
    else        asm volatile("s_waitcnt vmcnt(4)" ::: "memory");
    __builtin_amdgcn_sched_barrier(0);
    {
      short8 a = ((t & 1) == 0) ? pack2(va0, va1) : pack2(vb0, vb1);
      *(short8*)(&As[t & 1][arow * 32 + aoct * 8]) = a;
      if constexpr (FUSE) xa[t] = a;     // free retention (reg copy)
    }
    asm volatile("s_waitcnt lgkmcnt(0)" ::: "memory");
    __builtin_amdgcn_sched_barrier(0);
    __builtin_amdgcn_s_barrier();
    // ---- issue next loads (stay in flight across barriers) ----
    if (t < 15) {                       // B(t+1) -> other set
      const unsigned short* bp = bsrc + (t + 1) * 8192;
      if (((t + 1) & 1) == 0) GLOAD_B(br0, bp);
      else                    GLOAD_B(br1, bp);
    }
    if (t < 14) {                       // A(t+2) -> just-consumed set
      const float* pp = xsrc + (t + 2) * 32;
      if ((t & 1) == 0) GLOAD_A(va0, va1, pp);
      else              GLOAD_A(vb0, vb1, pp);
    }
    // ---- retire B(t) regs ----
    if (t < 14)       asm volatile("s_waitcnt vmcnt(8)" ::: "memory");
    else if (t == 14) asm volatile("s_waitcnt vmcnt(6)" ::: "memory");
    else              asm volatile("s_waitcnt vmcnt(0)" ::: "memory");
    __builtin_amdgcn_sched_barrier(0);
    // ---- compute(t): 4 A-frags x 4 B-frags, 16 MFMA per wave ----
    short8 af[4];
    #pragma unroll
    for (int m = 0; m < 4; ++m)
      af[m] = *(const short8*)(&As[t & 1][(m * 16 + l15) * 32 + l4 * 8]);
    const short8* bcur = ((t & 1) == 0) ? br0 : br1;
    #pragma unroll
    for (int n = 0; n < 4; ++n)
      #pragma unroll
      for (int m = 0; m < 4; ++m)
        acc[m][n] = __builtin_amdgcn_mfma_f32_16x16x32_bf16(af[m], bcur[n], acc[m][n], 0, 0, 0);
  }

  // epilogue: score = sum_c tanh(H + b1[c]) * W2[c]  over this wave's 64 cols
  float rowacc[16];
  #pragma unroll
  for (int i = 0; i < 16; i++) rowacc[i] = 0.f;
  #pragma unroll
  for (int n = 0; n < 4; n++) {
    int c = wn * 64 + n * 16 + l15;
    float b1c = b1[c];
    float w2c = W2[c];
    #pragma unroll
    for (int m = 0; m < 4; m++)
      #pragma unroll
      for (int j = 0; j < 4; j++) {
        float h = fast_tanh(acc[m][n][j] + b1c);
        rowacc[m * 4 + j] = fmaf(h, w2c, rowacc[m * 4 + j]);
      }
  }
  #pragma unroll
  for (int i = 0; i < 16; i++) {
    float v = rowacc[i];
    v += __shfl_xor(v, 1, 64);
    v += __shfl_xor(v, 2, 64);
    v += __shfl_xor(v, 4, 64);
    v += __shfl_xor(v, 8, 64);
    rowacc[i] = v;
  }
  if (l15 == 0) {
    #pragma unroll
    for (int m = 0; m < 4; m++)
      #pragma unroll
      for (int j = 0; j < 4; j++)
        scpart[wn * 64 + m * 16 + l4 * 4 + j] = rowacc[m * 4 + j];
  }
  __syncthreads();

  // es + block partial Z  (first wave only)
  if (tid < 64) {
    float sv = scpart[0 * 64 + tid] + scpart[1 * 64 + tid] +
               scpart[2 * 64 + tid] + scpart[3 * 64 + tid];
    float ev = __expf(sv);
    es_s[tid] = ev;
    if constexpr (!FUSE) es[row0 + tid] = ev;
    float v = ev;
    v += __shfl_xor(v, 1, 64);
    v += __shfl_xor(v, 2, 64);
    v += __shfl_xor(v, 4, 64);
    v += __shfl_xor(v, 8, 64);
    v += __shfl_xor(v, 16, 64);
    v += __shfl_xor(v, 32, 64);
    if (tid == 0) partials[blockIdx.x] = v;
  }
  __syncthreads();   // es_s visible; scpart dead (pacc may alias it now)

  if constexpr (FUSE) {
    // ---- phase 2: private per-bag partial sums from retained xa ----
    float* pacc = (float*)smem;                 // [16][512], aliases As+scpart
    const int g = wn * 4 + (lane >> 4);         // row-quad group 0..15
    const bool wr = ((lane & 12) == 0);         // one writer lane per quad

    int bag = 0; long cum = 0;
    while (bag + 1 < nbags && cum + (long)bag_sizes[bag] <= row0) {
      cum += bag_sizes[bag]; ++bag;
    }
    long bagEnd = cum + (long)bag_sizes[bag];

    int segidx = 0;
    int rs = 0;
    while (rs < 64) {                           // uniform across block
      int se = (int)(bagEnd - row0 < 64 ? bagEnd - row0 : 64);
      if (se < rs) se = rs;
      float wme = (arow >= rs && arow < se) ? es_s[arow] : 0.f;
      #pragma unroll
      for (int t = 0; t < 16; ++t) {
        const unsigned int* ui = (const unsigned int*)&xa[t];
        float p[8];
        #pragma unroll
        for (int d = 0; d < 4; ++d) {
          p[2 * d]     = __uint_as_float(ui[d] << 16) * wme;
          p[2 * d + 1] = __uint_as_float(ui[d] & 0xffff0000u) * wme;
        }
        #pragma unroll
        for (int e = 0; e < 8; ++e) {           // fold arow bits 0,1
          p[e] += __shfl_xor(p[e], 4, 64);
          p[e] += __shfl_xor(p[e], 8, 64);
        }
        if (wr) {
          float* dst = &pacc[g * 512 + t * 32 + aoct * 8];
          *(float4*)dst       = (float4){p[0], p[1], p[2], p[3]};
          *(float4*)(dst + 4) = (float4){p[4], p[5], p[6], p[7]};
        }
      }
      __syncthreads();
      {                                         // fold 16 quad-groups
        int f = tid * 2;
        float tx = 0.f, ty = 0.f;
        #pragma unroll
        for (int gg = 0; gg < 16; ++gg) {
          float2 v = *(const float2*)&pacc[gg * 512 + f];
          tx += v.x; ty += v.y;
        }
        long blk = blockIdx.x;
        if (segidx == 0) {
          *(float2*)&partial_out[(blk * 2 + 0) * 512 + f] = (float2){tx, ty};
          if (tid == 0) bagid[blk * 2 + 0] = bag;
        } else if (segidx == 1) {
          *(float2*)&partial_out[(blk * 2 + 1) * 512 + f] = (float2){tx, ty};
          if (tid == 0) bagid[blk * 2 + 1] = bag;
        } else {                                // rare: >2 segments
          atomicAdd(&outAcc[(long)bag * 512 + f],     tx);
          atomicAdd(&outAcc[(long)bag * 512 + f + 1], ty);
        }
      }
      __syncthreads();                          // pacc reusable
      ++segidx;
      rs = se;
      if (rs < 64) {
        ++bag;
        if (bag >= nbags) { bagEnd = row0 + 64; bag = nbags - 1; }
        else bagEnd += (long)bag_sizes[bag];
      }
    }
    if (segidx < 2) {                           // zero unused slot 1
      int f = tid * 2;
      *(float2*)&partial_out[((long)blockIdx.x * 2 + 1) * 512 + f] =
          (float2){0.f, 0.f};
      if (tid == 0) bagid[blockIdx.x * 2 + 1] = -1;
    }
  }
}

// K2-reduce (FUSE): out[bag] = invZ * (sum of matching private partials
// + outAcc[bag]).  Fully overwrites out -> re-poison safe, zero atomics.
__global__ void __launch_bounds__(256)
k2_reduce(const int* __restrict__ bag_sizes, int nbags,
          const float* __restrict__ partials, int nblk,
          const int* __restrict__ bagid,
          const float* __restrict__ partial_out,
          const float* __restrict__ outAcc,
          float* __restrict__ out) {
  __shared__ float wred[4];
  __shared__ float invZ_s;
  const int tid = threadIdx.x;
  const int bag = blockIdx.x;

  float s = 0.f;
  for (int j = tid; j < nblk; j += 256) s += partials[j];
  #pragma unroll
  for (int m = 1; m < 64; m <<= 1) s += __shfl_xor(s, m, 64);
  if ((tid & 63) == 0) wred[tid >> 6] = s;
  __syncthreads();
  if (tid == 0) invZ_s = 1.0f / (wred[0] + wred[1] + wred[2] + wred[3]);
  __syncthreads();
  const float invZ = invZ_s;

  long off = 0;
  for (int b = 0; b < bag; ++b) off += bag_sizes[b];
  const int size = bag_sizes[bag];

  const int f = tid * 2;
  float tx = outAcc[(long)bag * 512 + f];
  float ty = outAcc[(long)bag * 512 + f + 1];
  if (size > 0) {
    int b0 = (int)(off >> 6);
    int b1 = (int)((off + size - 1) >> 6);
    for (int blk = b0; blk <= b1; ++blk) {
      #pragma unroll
      for (int slot = 0; slot < 2; ++slot) {
        if (bagid[blk * 2 + slot] == bag) {
          float2 v = *(const float2*)&partial_out[((long)blk * 2 + slot) * 512 + f];
          tx += v.x; ty += v.y;
        }
      }
    }
  }
  out[(long)bag * 512 + f]     = tx * invZ;
  out[(long)bag * 512 + f + 1] = ty * invZ;
}

// ---- fallback path (tiny ws): R5-proven k2b + fp32 k3 ----
__global__ void __launch_bounds__(256)
k2b_finish(const float* __restrict__ partials, int nparts, float* __restrict__ invZ) {
  int tid = threadIdx.x;
  float s = 0.f;
  for (int j = tid; j < nparts; j += 256) s += partials[j];
  #pragma unroll
  for (int m = 1; m < 64; m <<= 1) s += __shfl_xor(s, m, 64);
  __shared__ float wred[4];
  if ((tid & 63) == 0) wred[tid >> 6] = s;
  __syncthreads();
  if (tid == 0) invZ[0] = 1.0f / (wred[0] + wred[1] + wred[2] + wred[3]);
}

__global__ void __launch_bounds__(256)
k3_bagsum(const float* __restrict__ X, const int* __restrict__ bag_sizes,
          const float* __restrict__ es, const float* __restrict__ invZp,
          float* __restrict__ out, int nbags) {
  const int tid = threadIdx.x;
  const int f   = (tid & 127) * 4;
  const int r   = tid >> 7;
  const int bag = blockIdx.x >> 4;
  const int ic  = blockIdx.x & 15;
  int start = 0;
  for (int b = 0; b < bag; ++b) start += bag_sizes[b];
  const int size = bag_sizes[bag];
  const int end = start + size;
  const int chunk = (size + 15) >> 4;
  int i0 = start + ic * chunk;
  int i1 = min(i0 + chunk, end);
  float ax = 0.f, ay = 0.f, az = 0.f, aw = 0.f;
  for (int i = i0 + r; i < i1; i += 2) {
    float w = es[i];
    float4 x = *(const float4*)(X + (size_t)i * FDIM + f);
    ax = fmaf(x.x, w, ax); ay = fmaf(x.y, w, ay);
    az = fmaf(x.z, w, az); aw = fmaf(x.w, w, aw);
  }
  __shared__ float4 red[128];
  if (r == 1) red[tid & 127] = (float4){ax, ay, az, aw};
  __syncthreads();
  if (r == 0) {
    float4 o = red[tid];
    float invZ = invZp[0];
    ax = (ax + o.x) * invZ; ay = (ay + o.y) * invZ;
    az = (az + o.z) * invZ; aw = (aw + o.w) * invZ;
    float* op = out + (size_t)bag * FDIM + f;
    atomicAdd(op + 0, ax); atomicAdd(op + 1, ay);
    atomicAdd(op + 2, az); atomicAdd(op + 3, aw);
  }
}

extern "C" void kernel_launch(void* const* d_in, const int* in_sizes, int n_in,
                              void* d_out, int out_size, void* d_ws, size_t ws_size,
                              hipStream_t stream) {
  const float* X         = (const float*)d_in[0];
  const int*   bag_sizes = (const int*)d_in[1];
  const float* W1        = (const float*)d_in[2];
  const float* b1        = (const float*)d_in[3];
  const float* W2        = (const float*)d_in[4];
  // b2 (d_in[5]) cancels in the global softmax — unused.
  float* out = (float*)d_out;

  const int T     = in_sizes[0] / FDIM;   // 131072
  const int nbags = in_sizes[1];          // 64
  const int nblk  = T / 64;               // 2048

  char* ws = (char*)d_ws;
  unsigned short* W1B = (unsigned short*)ws;                  // 262144 B
  float* partials  = (float*)(ws + 262144);                   // 8192 B
  float* es        = (float*)(ws + 270336);                   // 524288 B (fb)
  float* invZ      = (float*)(ws + 794624);                   // 4 B (fb)
  int*   bagid     = (int*)(ws + 1048576);                    // 16384 B
  float* outAcc    = (float*)(ws + 1064960);                  // 131072 B
  float* partial_out = (float*)(ws + 1196032);                // 8388608 B
  const size_t NEED = 1196032 + (size_t)nblk * 2 * 512 * 4;

  const bool fuse = (ws_size >= NEED);

  hipLaunchKernelGGL(k0_pack_w1, dim3(512), dim3(256), 0, stream,
                     W1, W1B, out, fuse ? outAcc : (float*)nullptr);
  if (fuse) {
    hipLaunchKernelGGL(k1_scores<true>, dim3(nblk), dim3(256), 0, stream,
                       X, W1B, b1, W2, es, partials,
                       partial_out, bagid, outAcc, bag_sizes, nbags);
    hipLaunchKernelGGL(k2_reduce, dim3(nbags), dim3(256), 0, stream,
                       bag_sizes, nbags, partials, nblk,
                       bagid, partial_out, outAcc, out);
  } else {
    hipLaunchKernelGGL(k1_scores<false>, dim3(nblk), dim3(256), 0, stream,
                       X, W1B, b1, W2, es, partials,
                       (float*)nullptr, (int*)nullptr, (float*)nullptr,
                       bag_sizes, nbags);
    hipLaunchKernelGGL(k2b_finish, dim3(1), dim3(256), 0, stream,
                       partials, nblk, invZ);
    hipLaunchKernelGGL(k3_bagsum, dim3(nbags * 16), dim3(256), 0, stream,
                       X, bag_sizes, es, invZ, out, nbags);
  }
}

// Round 10
// 105.973 us; speedup vs baseline: 3.3562x; 1.2792x over previous
//
#include <hip/hip_runtime.h>

typedef __attribute__((ext_vector_type(8))) short short8;
typedef __attribute__((ext_vector_type(4))) float floatx4;

#define FDIM 512
#define HDIM 256

__device__ __forceinline__ unsigned short f2bf(float f) {
  unsigned int u = __float_as_uint(f);
  u += 0x7fffu + ((u >> 16) & 1u);   // round-to-nearest-even
  return (unsigned short)(u >> 16);
}

__device__ __forceinline__ short8 pack2(floatx4 a, floatx4 b) {
  short8 r;
  r[0] = (short)f2bf(a[0]); r[1] = (short)f2bf(a[1]);
  r[2] = (short)f2bf(a[2]); r[3] = (short)f2bf(a[3]);
  r[4] = (short)f2bf(b[0]); r[5] = (short)f2bf(b[1]);
  r[6] = (short)f2bf(b[2]); r[7] = (short)f2bf(b[3]);
  return r;
}

__device__ __forceinline__ float fast_tanh(float x) {
  x = fminf(15.0f, fmaxf(-15.0f, x));
  float e = __expf(2.0f * x);
  return (e - 1.0f) / (e + 1.0f);
}

// A: 2 x global_load_dwordx4 (8 floats), counted in the manual vmcnt ledger.
#define GLOAD_A(r0, r1, p)                                                     \
  do {                                                                         \
    asm volatile("global_load_dwordx4 %0, %1, off"                             \
                 : "=v"(r0) : "v"(p) : "memory");                              \
    asm volatile("global_load_dwordx4 %0, %1, off offset:16"                   \
                 : "=v"(r1) : "v"(p) : "memory");                              \
  } while (0)

// B: 4 x global_load_dwordx4 (4 short8 fragments, 16-col stride = 256 B).
#define GLOAD_B(r, p)                                                          \
  do {                                                                         \
    asm volatile("global_load_dwordx4 %0, %1, off"                             \
                 : "=v"(r[0]) : "v"(p) : "memory");                            \
    asm volatile("global_load_dwordx4 %0, %1, off offset:256"                  \
                 : "=v"(r[1]) : "v"(p) : "memory");                            \
    asm volatile("global_load_dwordx4 %0, %1, off offset:512"                  \
                 : "=v"(r[2]) : "v"(p) : "memory");                            \
    asm volatile("global_load_dwordx4 %0, %1, off offset:768"                  \
                 : "=v"(r[3]) : "v"(p) : "memory");                            \
  } while (0)

// K0: pack W1 [512][256] fp32 -> W1B bf16 fragment-major:
// element index = s*8192 + oct*2048 + n*8 + e   (k = s*32 + oct*8 + e)
// Blocks < 128 also zero out (re-poison safety; out accumulated by atomics).
__global__ void __launch_bounds__(256)
k0_pack_w1(const float* __restrict__ W1, unsigned short* __restrict__ W1B,
           float* __restrict__ out) {
  int tid = threadIdx.x;
  int idx = blockIdx.x * 256 + tid;           // 0..131071
  if (blockIdx.x < 128) out[blockIdx.x * 256 + tid] = 0.0f;   // 32768 floats
  int k = idx >> 8;                           // 0..511
  int n = idx & 255;
  int s = k >> 5, r = k & 31, oct = r >> 3, e = r & 7;
  W1B[s * 8192 + oct * 2048 + n * 8 + e] = f2bf(W1[idx]);
}

// K1: es = exp(score) per row + per-block partial Z.  BYTE-IDENTICAL to the
// round-5 proven kernel (107 µs path).  64 rows/block, 4 waves, BK=32,
// 16 steps, LDS ~9 KB, B in registers, counted-vmcnt pipeline, no min-waves
// cap below demand (R4 spill lesson: spilled asm-load regs corrupt the
// ledger).  Ledger (A=2 ops, B=4 ops, B depth-1, A depth-2):
//   prologue A0(2) B0(4) A1(2) = 8 outstanding
//   step t head: [A(t)2 B(t)4 A(t+1)2] -> vmcnt(6) retires A(t) (t=15: 4)
//   post-barrier: issue B(t+1) (t<15), A(t+2) (t<14) -> 12 outstanding
//   compute wait: vmcnt(8) retires B(t)  (t=14: 6; t=15: 0)
// WAR on As[t&1]: readers of step t-2 drained via own lgkmcnt(0) before
// barrier(t-1); writer passes barrier(t-1) first -> one barrier/step safe.
__global__ void __launch_bounds__(256, 2)
k1_scores(const float* __restrict__ X,
          const unsigned short* __restrict__ W1B,
          const float* __restrict__ b1,
          const float* __restrict__ W2,
          float* __restrict__ es,
          float* __restrict__ partials) {
  __shared__ __align__(16) unsigned short As[2][2048];  // [buf][row64*32k] = 8 KB
  __shared__ float scpart[256];                         // [wn][row64]

  const int tid  = threadIdx.x;
  const int wn   = tid >> 6;          // 0..3 col-group
  const int lane = tid & 63;
  const int l15  = lane & 15;
  const int l4   = lane >> 4;
  const long row0 = (long)blockIdx.x * 64;

  floatx4 acc[4][4];
  #pragma unroll
  for (int m = 0; m < 4; m++)
    #pragma unroll
    for (int n = 0; n < 4; n++)
      acc[m][n] = (floatx4){0.f, 0.f, 0.f, 0.f};

  // A staging map: thread -> (row = tid>>2, octet = tid&3 -> 8 consecutive k)
  const int arow = tid >> 2;                    // 0..63
  const int aoct = tid & 3;                     // octet within 32-k step
  const float* xsrc = X + (row0 + arow) * FDIM + aoct * 8;
  // B fragment base for this lane: oct = l4, col = wn*64 + l15
  const unsigned short* bsrc = W1B + l4 * 2048 + (wn * 64 + l15) * 8;

  floatx4 va0, va1, vb0, vb1;            // 2 rotating A sets (depth-2)
  short8 br0[4], br1[4];                 // 2 rotating B sets (depth-1)

  // Prologue issue order: A(0), B(0)->set0, A(1)  => 8 outstanding
  GLOAD_A(va0, va1, xsrc);
  GLOAD_B(br0, bsrc);
  GLOAD_A(vb0, vb1, xsrc + 32);

  #pragma unroll
  for (int t = 0; t < 16; ++t) {
    // ---- retire A(t) regs ----
    if (t < 15) asm volatile("s_waitcnt vmcnt(6)" ::: "memory");
    else        asm volatile("s_waitcnt vmcnt(4)" ::: "memory");
    __builtin_amdgcn_sched_barrier(0);
    {
      short8 a = ((t & 1) == 0) ? pack2(va0, va1) : pack2(vb0, vb1);
      *(short8*)(&As[t & 1][arow * 32 + aoct * 8]) = a;
    }
    asm volatile("s_waitcnt lgkmcnt(0)" ::: "memory");
    __builtin_amdgcn_sched_barrier(0);
    __builtin_amdgcn_s_barrier();
    // ---- issue next loads (stay in flight across barriers) ----
    if (t < 15) {                       // B(t+1) -> other set
      const unsigned short* bp = bsrc + (t + 1) * 8192;
      if (((t + 1) & 1) == 0) GLOAD_B(br0, bp);
      else                    GLOAD_B(br1, bp);
    }
    if (t < 14) {                       // A(t+2) -> just-consumed set
      const float* pp = xsrc + (t + 2) * 32;
      if ((t & 1) == 0) GLOAD_A(va0, va1, pp);
      else              GLOAD_A(vb0, vb1, pp);
    }
    // ---- retire B(t) regs ----
    if (t < 14)       asm volatile("s_waitcnt vmcnt(8)" ::: "memory");
    else if (t == 14) asm volatile("s_waitcnt vmcnt(6)" ::: "memory");
    else              asm volatile("s_waitcnt vmcnt(0)" ::: "memory");
    __builtin_amdgcn_sched_barrier(0);
    // ---- compute(t): 4 A-frags x 4 B-frags, 16 MFMA per wave ----
    short8 af[4];
    #pragma unroll
    for (int m = 0; m < 4; ++m)
      af[m] = *(const short8*)(&As[t & 1][(m * 16 + l15) * 32 + l4 * 8]);
    const short8* bcur = ((t & 1) == 0) ? br0 : br1;
    #pragma unroll
    for (int n = 0; n < 4; ++n)
      #pragma unroll
      for (int m = 0; m < 4; ++m)
        acc[m][n] = __builtin_amdgcn_mfma_f32_16x16x32_bf16(af[m], bcur[n], acc[m][n], 0, 0, 0);
  }

  // epilogue: score = sum_c tanh(H + b1[c]) * W2[c]  over this wave's 64 cols
  float rowacc[16];
  #pragma unroll
  for (int i = 0; i < 16; i++) rowacc[i] = 0.f;
  #pragma unroll
  for (int n = 0; n < 4; n++) {
    int c = wn * 64 + n * 16 + l15;
    float b1c = b1[c];
    float w2c = W2[c];
    #pragma unroll
    for (int m = 0; m < 4; m++)
      #pragma unroll
      for (int j = 0; j < 4; j++) {
        float h = fast_tanh(acc[m][n][j] + b1c);
        rowacc[m * 4 + j] = fmaf(h, w2c, rowacc[m * 4 + j]);
      }
  }
  #pragma unroll
  for (int i = 0; i < 16; i++) {
    float v = rowacc[i];
    v += __shfl_xor(v, 1, 64);
    v += __shfl_xor(v, 2, 64);
    v += __shfl_xor(v, 4, 64);
    v += __shfl_xor(v, 8, 64);
    rowacc[i] = v;
  }
  if (l15 == 0) {
    #pragma unroll
    for (int m = 0; m < 4; m++)
      #pragma unroll
      for (int j = 0; j < 4; j++)
        scpart[wn * 64 + m * 16 + l4 * 4 + j] = rowacc[m * 4 + j];
  }
  __syncthreads();

  // es (global) + block partial Z  (first wave only)
  if (tid < 64) {
    float sv = scpart[0 * 64 + tid] + scpart[1 * 64 + tid] +
               scpart[2 * 64 + tid] + scpart[3 * 64 + tid];
    float ev = __expf(sv);
    es[row0 + tid] = ev;
    float v = ev;
    v += __shfl_xor(v, 1, 64);
    v += __shfl_xor(v, 2, 64);
    v += __shfl_xor(v, 4, 64);
    v += __shfl_xor(v, 8, 64);
    v += __shfl_xor(v, 16, 64);
    v += __shfl_xor(v, 32, 64);
    if (tid == 0) partials[blockIdx.x] = v;
  }
}

// K3 (REVERSED): out[bag] += invZ * sum es[i] * X[i], reading X TAIL-FIRST.
// Rationale: X (268 MB) slightly exceeds L3 (256 MB); forward-after-forward
// streaming hits the LRU pathology (each row evicted just before its re-read
// -> FETCH ~135 MB).  k1 streams X forward, so k3 streams BACKWARD: reversed
// block mapping (low blockIdx -> last chunks, dispatched first) + descending
// row iteration inside each chunk.  The ~256 MB k1 left resident is then hit
// (~12 MB head misses only), and k3 leaves the HEAD resident for the next
// iteration's forward k1 -> steady-state both passes mostly L3-served.
// Also folds k2b: per-block redundant invZ from partials (8 KB, L2-hot).
__global__ void __launch_bounds__(256)
k3_bagsum(const float* __restrict__ X, const int* __restrict__ bag_sizes,
          const float* __restrict__ es,
          const float* __restrict__ partials, int nparts,
          float* __restrict__ out, int nbags) {
  __shared__ float wred[4];
  __shared__ float invZ_s;
  __shared__ float4 red[128];
  const int tid = threadIdx.x;

  // invZ (folded k2b): sum 2048 partials, 8 iters/thread, L2-hot.
  {
    float s = 0.f;
    for (int j = tid; j < nparts; j += 256) s += partials[j];
    #pragma unroll
    for (int m = 1; m < 64; m <<= 1) s += __shfl_xor(s, m, 64);
    if ((tid & 63) == 0) wred[tid >> 6] = s;
    __syncthreads();
    if (tid == 0) invZ_s = 1.0f / (wred[0] + wred[1] + wred[2] + wred[3]);
    __syncthreads();
  }

  // Reversed mapping: block 0 -> last chunk of last bag (tail of X).
  const int rb  = (int)gridDim.x - 1 - (int)blockIdx.x;
  const int bag = rb >> 4;
  const int ic  = rb & 15;
  const int f   = (tid & 127) * 4;     // 0..508
  const int r   = tid >> 7;            // 0 or 1

  int start = 0;
  for (int b = 0; b < bag; ++b) start += bag_sizes[b];
  const int size = bag_sizes[bag];
  const int end = start + size;
  const int chunk = (size + 15) >> 4;
  int i0 = start + ic * chunk;
  int i1 = min(i0 + chunk, end);

  float ax = 0.f, ay = 0.f, az = 0.f, aw = 0.f;
  const int base = i0 + r;
  if (i1 > base) {
    int i = i1 - 1;
    i -= ((i - base) & 1);             // largest index == base (mod 2)
    for (; i >= base; i -= 2) {        // DESCENDING rows
      float w = es[i];
      float4 x = *(const float4*)(X + (size_t)i * FDIM + f);
      ax = fmaf(x.x, w, ax); ay = fmaf(x.y, w, ay);
      az = fmaf(x.z, w, az); aw = fmaf(x.w, w, aw);
    }
  }
  if (r == 1) red[tid & 127] = (float4){ax, ay, az, aw};
  __syncthreads();
  if (r == 0) {
    float4 o = red[tid];
    float invZ = invZ_s;
    ax = (ax + o.x) * invZ; ay = (ay + o.y) * invZ;
    az = (az + o.z) * invZ; aw = (aw + o.w) * invZ;
    float* op = out + (size_t)bag * FDIM + f;
    atomicAdd(op + 0, ax); atomicAdd(op + 1, ay);
    atomicAdd(op + 2, az); atomicAdd(op + 3, aw);
  }
}

extern "C" void kernel_launch(void* const* d_in, const int* in_sizes, int n_in,
                              void* d_out, int out_size, void* d_ws, size_t ws_size,
                              hipStream_t stream) {
  const float* X         = (const float*)d_in[0];
  const int*   bag_sizes = (const int*)d_in[1];
  const float* W1        = (const float*)d_in[2];
  const float* b1        = (const float*)d_in[3];
  const float* W2        = (const float*)d_in[4];
  // b2 (d_in[5]) cancels in the global softmax — unused.
  float* out = (float*)d_out;

  const int T     = in_sizes[0] / FDIM;   // 131072
  const int nbags = in_sizes[1];          // 64
  const int nblk  = T / 64;               // 2048

  char* ws = (char*)d_ws;
  unsigned short* W1B = (unsigned short*)ws;                     // 262144 B
  float* es       = (float*)(ws + 262144);                       // 524288 B
  float* partials = (float*)(ws + 262144 + 524288);              // 8192 B

  hipLaunchKernelGGL(k0_pack_w1, dim3(512), dim3(256), 0, stream, W1, W1B, out);
  hipLaunchKernelGGL(k1_scores, dim3(nblk), dim3(256), 0, stream,
                     X, W1B, b1, W2, es, partials);
  hipLaunchKernelGGL(k3_bagsum, dim3(nbags * 16), dim3(256), 0, stream,
                     X, bag_sizes, es, partials, nblk, out, nbags);
}